// Round 16
// baseline (354.221 us; speedup 1.0000x reference)
//
#include <hip/hip_runtime.h>
#include <hip/hip_fp16.h>

// ---------------------------------------------------------------------------
// 3-layer GAT (heads=1) forward. N=100000, E=1600000, Ep=E+N, G=128,
// ND=16, ED=2, H=32.
// R16: k_agg 16-wide gather unroll (L3-latency-bound at 8-wide: 63MB L2-miss
// traffic at only 1.4TB/s, 59% occ -> more MLP); k_binB 8192 edges/block
// (longer per-bucket runs -> fewer split lines + half the reservations).
// Carried: R15 structure (colsum-in-binB, flagged self-loops, packed-half2
// x1/x2, 1-block scan), 32-lane agg body + fp16 h (R8), NT rec loads (R7),
// LDS bucket sort (R6), single-pass binC (R14), hproj0/Wf + v-scalar
// readout (R13/R14), no-atomics rule, no in-agg GEMV (R13).
// ---------------------------------------------------------------------------

#define NBUCK_SHIFT 8
#define NBUCK_MAX 512
#define CAP 6144   // max staged edges per 256-node bucket (mean ~4350, max ~4650)
#define SLF_BIT 0x00800000u   // self-loop flag in rec.x

// ---- fused preprocessing: [hist | (Wf + bounds)] --------------------------
__global__ void k_pre(const int* __restrict__ ei1, int* __restrict__ bucket_cnt,
                      const int* __restrict__ batch, int* __restrict__ bounds,
                      const float* __restrict__ Wne, const float* __restrict__ bne,
                      const float* __restrict__ W0, float* __restrict__ wf,
                      int n, int e, int ep, int nbH) {
    int b = blockIdx.x, t = threadIdx.x;
    if (b < nbH) {
        __shared__ int lh[NBUCK_MAX];
        lh[t] = 0; lh[t + 256] = 0;
        __syncthreads();
        int base = b * 4096;
#pragma unroll
        for (int i = 0; i < 16; ++i) {
            int gid = base + i * 256 + t;
            if (gid < ep) {
                int d = (gid < e) ? ei1[gid] : gid - e;
                atomicAdd(&lh[d >> NBUCK_SHIFT], 1);
            }
        }
        __syncthreads();
        if (lh[t]) atomicAdd(&bucket_cnt[t], lh[t]);
        if (lh[t + 256]) atomicAdd(&bucket_cnt[t + 256], lh[t + 256]);
        return;
    }
    for (int i = t; i < 288; i += 256) {
        int m = i >> 5, j = i & 31;
        float a = 0.f;
        for (int k = 0; k < 16; ++k) a += Wne[m * 16 + k] * W0[k * 32 + j];
        wf[i] = a;
    }
    if (t < 32) {
        float a = 0.f;
        for (int k = 0; k < 16; ++k) a += bne[k] * W0[k * 32 + t];
        wf[288 + t] = a;
    }
    for (int g = t; g <= 128; g += 256) {
        if (g == 128) { bounds[128] = n; continue; }
        int lo = 0, hi = n;
        while (lo < hi) {
            int mid = (lo + hi) >> 1;
            if (batch[mid] < g) lo = mid + 1; else hi = mid;
        }
        bounds[g] = lo;
    }
}

// Layer-0 projection straight from raw node features: h0 = nf @ Wf + bf.
__global__ void k_hproj0(const float* __restrict__ nf, const float* __restrict__ wf,
                         const float* __restrict__ as_, const float* __restrict__ ad_,
                         unsigned int* __restrict__ h2, float* __restrict__ asrc,
                         float* __restrict__ adst, int n) {
    int node = blockIdx.x * 8 + (threadIdx.x >> 5);
    int j = threadIdx.x & 31;
    if (node >= n) return;
    const float* xr = nf + node * 9;
    float acc = wf[288 + j];
#pragma unroll
    for (int m = 0; m < 9; ++m) acc += xr[m] * wf[m * 32 + j];
    float accp = __shfl_down(acc, 1, 32);
    if ((j & 1) == 0) {
        __half2 hh = __floats2half2_rn(acc, accp);
        h2[(size_t)node * 16 + (j >> 1)] = *reinterpret_cast<unsigned int*>(&hh);
    }
    float r1 = acc * as_[j], r2 = acc * ad_[j];
#pragma unroll
    for (int off = 16; off > 0; off >>= 1) {
        r1 += __shfl_xor(r1, off, 32);
        r2 += __shfl_xor(r2, off, 32);
    }
    if (j == 0) { asrc[node] = r1; adst[node] = r2; }
}

__device__ __forceinline__ float2 h2f2u(unsigned int hw) {
    __half2 hh = *reinterpret_cast<__half2*>(&hw);
    return make_float2(__low2float(hh), __high2float(hh));
}

// Mid-layer projection: h = x @ W, x packed half2, W in LDS.
__global__ void k_hproj(const unsigned int* __restrict__ xh, const float* __restrict__ W,
                        const float* __restrict__ as_, const float* __restrict__ ad_,
                        unsigned int* __restrict__ h2, float* __restrict__ asrc,
                        float* __restrict__ adst, int n) {
    __shared__ float sW[1024];
    for (int i = threadIdx.x; i < 1024; i += 256) sW[i] = W[i];
    __syncthreads();
    int node = blockIdx.x * 8 + (threadIdx.x >> 5);
    int j = threadIdx.x & 31;
    if (node >= n) return;
    const unsigned int* xr = xh + (size_t)node * 16;
    float acc = 0.f;
#pragma unroll
    for (int w = 0; w < 16; ++w) {
        float2 f = h2f2u(xr[w]);
        acc += f.x * sW[(2 * w) * 32 + j] + f.y * sW[(2 * w + 1) * 32 + j];
    }
    float accp = __shfl_down(acc, 1, 32);
    if ((j & 1) == 0) {
        __half2 hh = __floats2half2_rn(acc, accp);
        h2[(size_t)node * 16 + (j >> 1)] = *reinterpret_cast<unsigned int*>(&hh);
    }
    float r1 = acc * as_[j], r2 = acc * ad_[j];
#pragma unroll
    for (int off = 16; off > 0; off >>= 1) {
        r1 += __shfl_xor(r1, off, 32);
        r2 += __shfl_xor(r2, off, 32);
    }
    if (j == 0) { asrc[node] = r1; adst[node] = r2; }
}

// Bucket-base scan (1 block).
__global__ void __launch_bounds__(512)
k_scan(const int* __restrict__ bucket_cnt, int* __restrict__ bucket_base,
       int* __restrict__ bcursor, int nbuck, int ep, int* __restrict__ rp, int n) {
    __shared__ int s[512];
    int t = threadIdx.x;
    int v = (t < nbuck) ? bucket_cnt[t] : 0;
    s[t] = v;
    __syncthreads();
    for (int o = 1; o < 512; o <<= 1) {
        int x = (t >= o) ? s[t - o] : 0;
        __syncthreads();
        s[t] += x;
        __syncthreads();
    }
    int ex = s[t] - v;
    if (t < nbuck) { bucket_base[t] = ex; bcursor[t] = ex; }
    if (t == 0) { bucket_base[nbuck] = ep; rp[n] = ep; }
}

// Phase B: stage edges grouped by bucket, 8192 edges/block (32/thread) --
// longer per-bucket runs, fewer reservations. Also computes ef colsum
// partials (per-wave, unique slots). Self-loop recs get flag bit31.
__global__ void k_binB(const int* __restrict__ ei0, const int* __restrict__ ei1,
                       const float* __restrict__ ea, const float* __restrict__ We,
                       const float* __restrict__ be, int* __restrict__ bcursor,
                       uint2* __restrict__ st, float2* __restrict__ partial,
                       int e, int ep) {
    __shared__ int lh[NBUCK_MAX], lcur[NBUCK_MAX];
    int t = threadIdx.x;
    lh[t] = 0; lh[t + 256] = 0;
    __syncthreads();
    int base = blockIdx.x * 8192;
    unsigned int sd[32], fh[32];
    int bk[32];
    float w00 = We[0], w10 = We[2], w20 = We[4];
    float w01 = We[1], w11 = We[3], w21 = We[5];
    float b0 = be[0], b1 = be[1];
    float cs0 = 0.f, cs1 = 0.f;
#pragma unroll
    for (int i = 0; i < 32; ++i) {
        int gid = base + i * 256 + t;
        bk[i] = -1;
        if (gid < ep) {
            int s, d;
            if (gid < e) {
                s = ei0[gid]; d = ei1[gid];
                const float* r = ea + (size_t)gid * 3;
                float a0 = r[0], a1 = r[1], a2 = r[2];
                float f0 = a0 * w00 + a1 * w10 + a2 * w20 + b0;
                float f1 = a0 * w01 + a1 * w11 + a2 * w21 + b1;
                cs0 += f0; cs1 += f1;
                sd[i] = ((unsigned int)s << NBUCK_SHIFT) | (unsigned int)(d & 255);
                __half2 hh = __floats2half2_rn(f0, f1);
                fh[i] = *reinterpret_cast<unsigned int*>(&hh);
            } else {
                s = d = gid - e;
                sd[i] = 0x80000000u | ((unsigned int)s << NBUCK_SHIFT)
                      | (unsigned int)(d & 255);
                fh[i] = 0;
            }
            bk[i] = d >> NBUCK_SHIFT;
            atomicAdd(&lh[bk[i]], 1);
        }
    }
#pragma unroll
    for (int off = 32; off > 0; off >>= 1) {
        cs0 += __shfl_xor(cs0, off, 64);
        cs1 += __shfl_xor(cs1, off, 64);
    }
    if ((t & 63) == 0)
        partial[(blockIdx.x << 2) + (t >> 6)] = make_float2(cs0, cs1);
    __syncthreads();
    if (lh[t] > 0) lcur[t] = atomicAdd(&bcursor[t], lh[t]);
    if (lh[t + 256] > 0) lcur[t + 256] = atomicAdd(&bcursor[t + 256], lh[t + 256]);
    __syncthreads();
#pragma unroll
    for (int i = 0; i < 32; ++i) {
        if (bk[i] >= 0) {
            int pos = atomicAdd(&lcur[bk[i]], 1);
            st[pos] = make_uint2(sd[i], fh[i]);
        }
    }
}

// Phase C: blocks [0,nbuck) sort one bucket each (single-pass, recs in
// registers); block nbuck reduces colsum partials -> consts.
__global__ void __launch_bounds__(512)
k_binC(const uint2* __restrict__ st, const int* __restrict__ bucket_base,
       int* __restrict__ rp, uint2* __restrict__ rec, int n, int nbuck,
       const float* __restrict__ We0, const float* __restrict__ ae0,
       const float* __restrict__ We1, const float* __restrict__ ae1,
       const float* __restrict__ We2, const float* __restrict__ ae2,
       const float2* __restrict__ partial, int nw, float einv,
       float* __restrict__ consts) {
    int k = blockIdx.x, t = threadIdx.x;
    if (k == nbuck) {
        __shared__ float r0[512], r1[512];
        float m0 = 0.f, m1 = 0.f;
        for (int i = t; i < nw; i += 512) {
            float2 v = partial[i];
            m0 += v.x; m1 += v.y;
        }
        r0[t] = m0; r1[t] = m1;
        __syncthreads();
        for (int o = 256; o > 0; o >>= 1) {
            if (t < o) { r0[t] += r0[t + o]; r1[t] += r1[t + o]; }
            __syncthreads();
        }
        if (t == 0) {
            float fm0 = r0[0] * einv, fm1 = r1[0] * einv;
            const float* We[3] = {We0, We1, We2};
            const float* ae[3] = {ae0, ae1, ae2};
            for (int l = 0; l < 3; ++l) {
                float c0 = 0.f, c1 = 0.f;
                for (int j = 0; j < 32; ++j) {
                    c0 += We[l][j] * ae[l][j];
                    c1 += We[l][32 + j] * ae[l][j];
                }
                consts[l * 2 + 0] = c0;
                consts[l * 2 + 1] = c1;
                consts[6 + l] = fm0 * c0 + fm1 * c1;
            }
        }
        return;
    }
    __shared__ int nh[256], ns[256];
    __shared__ uint2 rs[CAP];
    int s0 = bucket_base[k], s1 = bucket_base[k + 1];
    int cnt = s1 - s0;
    uint2 lv[12];
    if (t < 256) nh[t] = 0;
    __syncthreads();
#pragma unroll
    for (int u = 0; u < 12; ++u) {
        int i = s0 + u * 512 + t;
        if (i < s1) {
            uint2 v = st[i];
            lv[u] = v;
            atomicAdd(&nh[v.x & 255], 1);
        }
    }
    __syncthreads();
    if (t < 256) ns[t] = nh[t];
    __syncthreads();
    for (int o = 1; o < 256; o <<= 1) {
        int add = 0;
        if (t < 256 && t >= o) add = ns[t - o];
        __syncthreads();
        if (t < 256) ns[t] += add;
        __syncthreads();
    }
    int node0 = k << NBUCK_SHIFT;
    if (t < 256) {
        int startl = ns[t] - nh[t];
        if (node0 + t < n) rp[node0 + t] = s0 + startl;
        nh[t] = startl;
    }
    __syncthreads();
#pragma unroll
    for (int u = 0; u < 12; ++u) {
        int i = s0 + u * 512 + t;
        if (i < s1) {
            uint2 v = lv[u];
            int pos = atomicAdd(&nh[v.x & 255], 1);
            uint2 r = make_uint2(v.x >> NBUCK_SHIFT, v.y);
            if (pos < CAP) rs[pos] = r;
            else rec[s0 + pos] = r;
        }
    }
    __syncthreads();
    int m = cnt < CAP ? cnt : CAP;
    for (int i = t; i < m; i += 512)
        rec[s0 + i] = rs[i];
}

__device__ __forceinline__ float h2_get(const unsigned int* __restrict__ h2,
                                        int s, int word, bool hi) {
    unsigned int hw = h2[(size_t)s * 16 + word];
    __half2 hh = *reinterpret_cast<__half2*>(&hw);
    return hi ? __high2float(hh) : __low2float(hh);
}

// Fused edge-softmax + aggregation, 32-lane group per dst node.
// 16-wide gather unroll (L3-latency hiding). rec.x bit23 = self-loop flag.
template <bool STORE_X>
__global__ void k_agg(const int* __restrict__ rp, const uint2* __restrict__ rec,
                      const float* __restrict__ asrc, const float* __restrict__ adst,
                      const float* __restrict__ consts, const unsigned int* __restrict__ h2,
                      const float* __restrict__ bb, unsigned int* __restrict__ xout,
                      const float* __restrict__ wl3, float* __restrict__ vout,
                      int n, int layer) {
    int node = blockIdx.x * 8 + (threadIdx.x >> 5);
    int j = threadIdx.x & 31;
    if (node >= n) return;
    float c0 = consts[layer * 2], c1 = consts[layer * 2 + 1];
    float loopc = consts[6 + layer];
    int r0 = rp[node], r1 = rp[node + 1];
    float adn = adst[node];
    int word = j >> 1;
    bool hi = (j & 1) != 0;
    float acc = 0.f, psum = 0.f;
    for (int c = r0; c < r1; c += 32) {
        int i = c + j;
        float pe = 0.f; int s = 0;
        if (i < r1) {
            unsigned long long rv = __builtin_nontemporal_load(
                reinterpret_cast<const unsigned long long*>(rec + i));
            unsigned int sx = (unsigned int)(rv & 0xffffffffull);
            s = (int)(sx & 0x7fffffu);
            unsigned int fv = (unsigned int)(rv >> 32);
            __half2 hh = *reinterpret_cast<__half2*>(&fv);
            float ae = (sx & SLF_BIT) ? loopc
                     : (__low2float(hh) * c0 + __high2float(hh) * c1);
            float lg = asrc[s] + adn + ae;
            lg = lg > 0.f ? lg : 0.2f * lg;
            pe = __expf(lg);
        }
        psum += pe;
        int cnt = min(32, r1 - c);
        int t = 0;
        for (; t + 16 <= cnt; t += 16) {
            int ss[16]; float pp[16], hh[16];
#pragma unroll
            for (int u = 0; u < 16; ++u) ss[u] = __shfl(s, t + u, 32);
#pragma unroll
            for (int u = 0; u < 16; ++u) hh[u] = h2_get(h2, ss[u], word, hi);
#pragma unroll
            for (int u = 0; u < 16; ++u) pp[u] = __shfl(pe, t + u, 32);
#pragma unroll
            for (int u = 0; u < 16; ++u) acc += pp[u] * hh[u];
        }
        for (; t + 8 <= cnt; t += 8) {
            int ss[8]; float pp[8], hh[8];
#pragma unroll
            for (int u = 0; u < 8; ++u) ss[u] = __shfl(s, t + u, 32);
#pragma unroll
            for (int u = 0; u < 8; ++u) hh[u] = h2_get(h2, ss[u], word, hi);
#pragma unroll
            for (int u = 0; u < 8; ++u) pp[u] = __shfl(pe, t + u, 32);
#pragma unroll
            for (int u = 0; u < 8; ++u) acc += pp[u] * hh[u];
        }
        for (; t + 4 <= cnt; t += 4) {
            int ss[4]; float pp[4], hh[4];
#pragma unroll
            for (int u = 0; u < 4; ++u) ss[u] = __shfl(s, t + u, 32);
#pragma unroll
            for (int u = 0; u < 4; ++u) hh[u] = h2_get(h2, ss[u], word, hi);
#pragma unroll
            for (int u = 0; u < 4; ++u) pp[u] = __shfl(pe, t + u, 32);
#pragma unroll
            for (int u = 0; u < 4; ++u) acc += pp[u] * hh[u];
        }
        for (; t < cnt; ++t) {
            int st2 = __shfl(s, t, 32);
            float pt = __shfl(pe, t, 32);
            acc += pt * h2_get(h2, st2, word, hi);
        }
    }
#pragma unroll
    for (int off = 16; off > 0; off >>= 1) psum += __shfl_xor(psum, off, 32);
    float res = acc / (psum + 1e-16f) + bb[j];
    if (STORE_X) {
        float resp = __shfl_down(res, 1, 32);
        if ((j & 1) == 0) {
            __half2 hh = __floats2half2_rn(res, resp);
            xout[(size_t)node * 16 + (j >> 1)] = *reinterpret_cast<unsigned int*>(&hh);
        }
    }
    float v = res * wl3[j];
#pragma unroll
    for (int off = 16; off > 0; off >>= 1) v += __shfl_xor(v, off, 32);
    if (j == 0) vout[node] = v;
}

// Readout: one block per graph, sums the three per-node scalars. 1.2MB total.
__global__ void k_dotv(const float* __restrict__ v0, const float* __restrict__ v1,
                       const float* __restrict__ v2, const int* __restrict__ bounds,
                       const float* __restrict__ bl3, float* __restrict__ out) {
    __shared__ float red[256];
    int g = blockIdx.x, t = threadIdx.x;
    int s0 = bounds[g], s1 = bounds[g + 1];
    float acc = 0.f;
    for (int i = s0 + t; i < s1; i += 256) acc += v0[i] + v1[i] + v2[i];
    red[t] = acc;
    __syncthreads();
    for (int o = 128; o > 0; o >>= 1) {
        if (t < o) red[t] += red[t + o];
        __syncthreads();
    }
    if (t == 0) {
        float c = (float)(s1 - s0);
        if (c < 1.f) c = 1.f;
        out[g] = red[0] / c + bl3[0];
    }
}

extern "C" void kernel_launch(void* const* d_in, const int* in_sizes, int n_in,
                              void* d_out, int out_size, void* d_ws, size_t ws_size,
                              hipStream_t stream) {
    (void)n_in; (void)out_size; (void)ws_size;
    const float* nf    = (const float*)d_in[0];
    const int*   ei    = (const int*)d_in[1];
    const float* ea    = (const float*)d_in[2];
    const int*   batch = (const int*)d_in[3];
    const float* W_ne  = (const float*)d_in[4];
    const float* b_ne  = (const float*)d_in[5];
    const float* W_ee  = (const float*)d_in[6];
    const float* b_ee  = (const float*)d_in[7];
    const float* W_l3  = (const float*)d_in[8];
    const float* b_l3  = (const float*)d_in[9];
    const float *Wl[3], *asl[3], *adl[3], *Wel[3], *ael[3], *bbl[3];
    for (int l = 0; l < 3; ++l) {
        Wl[l]  = (const float*)d_in[10 + 6 * l];
        asl[l] = (const float*)d_in[11 + 6 * l];
        adl[l] = (const float*)d_in[12 + 6 * l];
        Wel[l] = (const float*)d_in[13 + 6 * l];
        ael[l] = (const float*)d_in[14 + 6 * l];
        bbl[l] = (const float*)d_in[15 + 6 * l];
    }

    const int n  = in_sizes[3];        // 100000
    const int e  = in_sizes[2] / 3;    // 1600000
    const int ep = e + n;
    const int* ei0 = ei;
    const int* ei1 = ei + e;
    const int nbuck = (n + 255) >> NBUCK_SHIFT;   // 391

    char* w = (char*)d_ws;
    size_t off = 0;
    auto alloc = [&](size_t b) { size_t o = off; off = (off + b + 255) & ~(size_t)255; return o; };
    unsigned int* x1h     = (unsigned int*)(w + alloc((size_t)n * 16 * 4));
    unsigned int* x2h     = (unsigned int*)(w + alloc((size_t)n * 16 * 4));
    unsigned int* h2a     = (unsigned int*)(w + alloc((size_t)n * 16 * 4));
    unsigned int* h2b     = (unsigned int*)(w + alloc((size_t)n * 16 * 4));
    float*        asrcA   = (float*)(w + alloc((size_t)n * 4));
    float*        adstA   = (float*)(w + alloc((size_t)n * 4));
    float*        asrcB   = (float*)(w + alloc((size_t)n * 4));
    float*        adstB   = (float*)(w + alloc((size_t)n * 4));
    float*        v0      = (float*)(w + alloc((size_t)n * 4));
    float*        v1      = (float*)(w + alloc((size_t)n * 4));
    float*        v2      = (float*)(w + alloc((size_t)n * 4));
    uint2*        st      = (uint2*)(w + alloc((size_t)ep * 8));
    uint2*        rec     = (uint2*)(w + alloc((size_t)ep * 8));
    int*          rp      = (int*)(w + alloc((size_t)(n + 1) * 4));
    int*          bcnt    = (int*)(w + alloc(NBUCK_MAX * 4));
    int*          bbase   = (int*)(w + alloc((NBUCK_MAX + 1) * 4));
    int*          bcur    = (int*)(w + alloc(NBUCK_MAX * 4));
    float2*       partial = (float2*)(w + alloc((size_t)8192 * 8));
    float*        consts  = (float*)(w + alloc(256));
    int*          bounds  = (int*)(w + alloc(129 * 4));
    float*        wfbuf   = (float*)(w + alloc(320 * 4));

    hipMemsetAsync(bcnt, 0, NBUCK_MAX * 4, stream);

    int nbH  = (ep + 4095) / 4096;       // 416 (hist)
    int nbB  = (ep + 8191) / 8192;       // 208 (binB)
    int nw   = nbB * 4;                  // colsum partial slots
    int nbN  = (n + 7) / 8;              // 12500

    k_pre<<<nbH + 1, 256, 0, stream>>>(ei1, bcnt, batch, bounds,
                                       W_ne, b_ne, Wl[0], wfbuf, n, e, ep, nbH);
    k_hproj0<<<nbN, 256, 0, stream>>>(nf, wfbuf, asl[0], adl[0],
                                      h2a, asrcA, adstA, n);
    k_scan<<<1, 512, 0, stream>>>(bcnt, bbase, bcur, nbuck, ep, rp, n);
    k_binB<<<nbB, 256, 0, stream>>>(ei0, ei1, ea, W_ee, b_ee, bcur, st,
                                    partial, e, ep);
    k_binC<<<nbuck + 1, 512, 0, stream>>>(st, bbase, rp, rec, n, nbuck,
                                          Wel[0], ael[0], Wel[1], ael[1],
                                          Wel[2], ael[2], partial, nw,
                                          1.0f / (float)e, consts);

    // layer 0: h2a/A -> x1h, v0
    k_agg<true><<<nbN, 256, 0, stream>>>(rp, rec, asrcA, adstA, consts, h2a,
                                         bbl[0], x1h, W_l3 + 0, v0, n, 0);
    k_hproj<<<nbN, 256, 0, stream>>>(x1h, Wl[1], asl[1], adl[1], h2b, asrcB, adstB, n);
    // layer 1: h2b/B -> x2h, v1
    k_agg<true><<<nbN, 256, 0, stream>>>(rp, rec, asrcB, adstB, consts, h2b,
                                         bbl[1], x2h, W_l3 + 32, v1, n, 1);
    k_hproj<<<nbN, 256, 0, stream>>>(x2h, Wl[2], asl[2], adl[2], h2a, asrcA, adstA, n);
    // layer 2: h2a/A -> v2 only
    k_agg<false><<<nbN, 256, 0, stream>>>(rp, rec, asrcA, adstA, consts, h2a,
                                          bbl[2], nullptr, W_l3 + 64, v2, n, 2);
    k_dotv<<<128, 256, 0, stream>>>(v0, v1, v2, bounds, b_l3, (float*)d_out);
}

// Round 17
// 344.662 us; speedup vs baseline: 1.0277x; 1.0277x over previous
//
#include <hip/hip_runtime.h>
#include <hip/hip_fp16.h>

// ---------------------------------------------------------------------------
// 3-layer GAT (heads=1) forward. N=100000, E=1600000, Ep=E+N, G=128,
// ND=16, ED=2, H=32.
// R17: clean revert to R15 (337.1us, best). R16 lesson: k_agg's 8-wide
// gather loop is a balanced VALU/L3 operating point -- 16-wide (+12 VGPR,
// batched shfls) raised VALUBusy 41->49% and dur 44->48us at unchanged
// FETCH; binB's 32-deep staging arrays also regressed. Loop shape has now
// defeated narrower (R9), wider (R16), and fused (R13) variants.
// Structure: colsum-in-binB + flagged self-loops, packed-half2 x1/x2,
// 1-block scan, 32-lane agg body + fp16 h (R8), NT rec loads (R7), LDS
// bucket sort (R6), single-pass binC (R14), hproj0/Wf + v-scalar readout
// (R13/R14), no-atomics-in-hot-path rule (R2/R4/R9-R11).
// ---------------------------------------------------------------------------

#define NBUCK_SHIFT 8
#define NBUCK_MAX 512
#define CAP 6144   // max staged edges per 256-node bucket (mean ~4350, max ~4650)
#define SLF_BIT 0x00800000u   // self-loop flag in rec.x (bit31 of sd >> 8)

// ---- fused preprocessing: [hist | (Wf + bounds)] --------------------------
__global__ void k_pre(const int* __restrict__ ei1, int* __restrict__ bucket_cnt,
                      const int* __restrict__ batch, int* __restrict__ bounds,
                      const float* __restrict__ Wne, const float* __restrict__ bne,
                      const float* __restrict__ W0, float* __restrict__ wf,
                      int n, int e, int ep, int nbH) {
    int b = blockIdx.x, t = threadIdx.x;
    if (b < nbH) {
        __shared__ int lh[NBUCK_MAX];
        lh[t] = 0; lh[t + 256] = 0;
        __syncthreads();
        int base = b * 4096;
#pragma unroll
        for (int i = 0; i < 16; ++i) {
            int gid = base + i * 256 + t;
            if (gid < ep) {
                int d = (gid < e) ? ei1[gid] : gid - e;
                atomicAdd(&lh[d >> NBUCK_SHIFT], 1);
            }
        }
        __syncthreads();
        if (lh[t]) atomicAdd(&bucket_cnt[t], lh[t]);
        if (lh[t + 256]) atomicAdd(&bucket_cnt[t + 256], lh[t + 256]);
        return;
    }
    // last block: fused layer-0 weights Wf = Wne@W0 (9x32), bf = bne@W0,
    // then graph bounds by binary search.
    for (int i = t; i < 288; i += 256) {
        int m = i >> 5, j = i & 31;
        float a = 0.f;
        for (int k = 0; k < 16; ++k) a += Wne[m * 16 + k] * W0[k * 32 + j];
        wf[i] = a;
    }
    if (t < 32) {
        float a = 0.f;
        for (int k = 0; k < 16; ++k) a += bne[k] * W0[k * 32 + t];
        wf[288 + t] = a;
    }
    for (int g = t; g <= 128; g += 256) {
        if (g == 128) { bounds[128] = n; continue; }
        int lo = 0, hi = n;
        while (lo < hi) {
            int mid = (lo + hi) >> 1;
            if (batch[mid] < g) lo = mid + 1; else hi = mid;
        }
        bounds[g] = lo;
    }
}

// Layer-0 projection straight from raw node features (x0 never exists):
// h0 = nf @ Wf + bf.  h stored packed half2.
__global__ void k_hproj0(const float* __restrict__ nf, const float* __restrict__ wf,
                         const float* __restrict__ as_, const float* __restrict__ ad_,
                         unsigned int* __restrict__ h2, float* __restrict__ asrc,
                         float* __restrict__ adst, int n) {
    int node = blockIdx.x * 8 + (threadIdx.x >> 5);
    int j = threadIdx.x & 31;
    if (node >= n) return;
    const float* xr = nf + node * 9;
    float acc = wf[288 + j];
#pragma unroll
    for (int m = 0; m < 9; ++m) acc += xr[m] * wf[m * 32 + j];
    float accp = __shfl_down(acc, 1, 32);
    if ((j & 1) == 0) {
        __half2 hh = __floats2half2_rn(acc, accp);
        h2[(size_t)node * 16 + (j >> 1)] = *reinterpret_cast<unsigned int*>(&hh);
    }
    float r1 = acc * as_[j], r2 = acc * ad_[j];
#pragma unroll
    for (int off = 16; off > 0; off >>= 1) {
        r1 += __shfl_xor(r1, off, 32);
        r2 += __shfl_xor(r2, off, 32);
    }
    if (j == 0) { asrc[node] = r1; adst[node] = r2; }
}

__device__ __forceinline__ float2 h2f2u(unsigned int hw) {
    __half2 hh = *reinterpret_cast<__half2*>(&hw);
    return make_float2(__low2float(hh), __high2float(hh));
}

// Mid-layer projection: h = x @ W, x packed half2 (16 words/node), W in LDS.
__global__ void k_hproj(const unsigned int* __restrict__ xh, const float* __restrict__ W,
                        const float* __restrict__ as_, const float* __restrict__ ad_,
                        unsigned int* __restrict__ h2, float* __restrict__ asrc,
                        float* __restrict__ adst, int n) {
    __shared__ float sW[1024];
    for (int i = threadIdx.x; i < 1024; i += 256) sW[i] = W[i];
    __syncthreads();
    int node = blockIdx.x * 8 + (threadIdx.x >> 5);
    int j = threadIdx.x & 31;
    if (node >= n) return;
    const unsigned int* xr = xh + (size_t)node * 16;
    float acc = 0.f;
#pragma unroll
    for (int w = 0; w < 16; ++w) {
        float2 f = h2f2u(xr[w]);
        acc += f.x * sW[(2 * w) * 32 + j] + f.y * sW[(2 * w + 1) * 32 + j];
    }
    float accp = __shfl_down(acc, 1, 32);
    if ((j & 1) == 0) {
        __half2 hh = __floats2half2_rn(acc, accp);
        h2[(size_t)node * 16 + (j >> 1)] = *reinterpret_cast<unsigned int*>(&hh);
    }
    float r1 = acc * as_[j], r2 = acc * ad_[j];
#pragma unroll
    for (int off = 16; off > 0; off >>= 1) {
        r1 += __shfl_xor(r1, off, 32);
        r2 += __shfl_xor(r2, off, 32);
    }
    if (j == 0) { asrc[node] = r1; adst[node] = r2; }
}

// Bucket-base scan (1 block).
__global__ void __launch_bounds__(512)
k_scan(const int* __restrict__ bucket_cnt, int* __restrict__ bucket_base,
       int* __restrict__ bcursor, int nbuck, int ep, int* __restrict__ rp, int n) {
    __shared__ int s[512];
    int t = threadIdx.x;
    int v = (t < nbuck) ? bucket_cnt[t] : 0;
    s[t] = v;
    __syncthreads();
    for (int o = 1; o < 512; o <<= 1) {
        int x = (t >= o) ? s[t - o] : 0;
        __syncthreads();
        s[t] += x;
        __syncthreads();
    }
    int ex = s[t] - v;
    if (t < nbuck) { bucket_base[t] = ex; bcursor[t] = ex; }
    if (t == 0) { bucket_base[nbuck] = ep; rp[n] = ep; }
}

// Phase B: stage edges grouped by bucket (8B uint2 {sd, half2}) AND compute
// ef column-sum partials (per-wave, unique slots, no atomics). Self-loop recs
// get flag bit31 in sd (no consts dependency here).
__global__ void k_binB(const int* __restrict__ ei0, const int* __restrict__ ei1,
                       const float* __restrict__ ea, const float* __restrict__ We,
                       const float* __restrict__ be, int* __restrict__ bcursor,
                       uint2* __restrict__ st, float2* __restrict__ partial,
                       int e, int ep) {
    __shared__ int lh[NBUCK_MAX], lcur[NBUCK_MAX];
    int t = threadIdx.x;
    lh[t] = 0; lh[t + 256] = 0;
    __syncthreads();
    int base = blockIdx.x * 4096;
    unsigned int sd[16], fh[16];
    int bk[16];
    float w00 = We[0], w10 = We[2], w20 = We[4];
    float w01 = We[1], w11 = We[3], w21 = We[5];
    float b0 = be[0], b1 = be[1];
    float cs0 = 0.f, cs1 = 0.f;
#pragma unroll
    for (int i = 0; i < 16; ++i) {
        int gid = base + i * 256 + t;
        bk[i] = -1;
        if (gid < ep) {
            int s, d;
            if (gid < e) {
                s = ei0[gid]; d = ei1[gid];
                const float* r = ea + (size_t)gid * 3;
                float a0 = r[0], a1 = r[1], a2 = r[2];
                float f0 = a0 * w00 + a1 * w10 + a2 * w20 + b0;
                float f1 = a0 * w01 + a1 * w11 + a2 * w21 + b1;
                cs0 += f0; cs1 += f1;
                sd[i] = ((unsigned int)s << NBUCK_SHIFT) | (unsigned int)(d & 255);
                __half2 hh = __floats2half2_rn(f0, f1);
                fh[i] = *reinterpret_cast<unsigned int*>(&hh);
            } else {
                s = d = gid - e;
                sd[i] = 0x80000000u | ((unsigned int)s << NBUCK_SHIFT)
                      | (unsigned int)(d & 255);
                fh[i] = 0;
            }
            bk[i] = d >> NBUCK_SHIFT;
            atomicAdd(&lh[bk[i]], 1);
        }
    }
    // per-wave colsum partial (real edges only)
#pragma unroll
    for (int off = 32; off > 0; off >>= 1) {
        cs0 += __shfl_xor(cs0, off, 64);
        cs1 += __shfl_xor(cs1, off, 64);
    }
    if ((t & 63) == 0)
        partial[(blockIdx.x << 2) + (t >> 6)] = make_float2(cs0, cs1);
    __syncthreads();
    if (lh[t] > 0) lcur[t] = atomicAdd(&bcursor[t], lh[t]);
    if (lh[t + 256] > 0) lcur[t + 256] = atomicAdd(&bcursor[t + 256], lh[t + 256]);
    __syncthreads();
#pragma unroll
    for (int i = 0; i < 16; ++i) {
        if (bk[i] >= 0) {
            int pos = atomicAdd(&lcur[bk[i]], 1);
            st[pos] = make_uint2(sd[i], fh[i]);
        }
    }
}

// Phase C: blocks [0,nbuck) sort one bucket each (single-pass, recs in
// registers); block nbuck reduces colsum partials -> consts
// ([0..5]=We@ae per layer, [6..8]=self-loop logit per layer).
__global__ void __launch_bounds__(512)
k_binC(const uint2* __restrict__ st, const int* __restrict__ bucket_base,
       int* __restrict__ rp, uint2* __restrict__ rec, int n, int nbuck,
       const float* __restrict__ We0, const float* __restrict__ ae0,
       const float* __restrict__ We1, const float* __restrict__ ae1,
       const float* __restrict__ We2, const float* __restrict__ ae2,
       const float2* __restrict__ partial, int nw, float einv,
       float* __restrict__ consts) {
    int k = blockIdx.x, t = threadIdx.x;
    if (k == nbuck) {
        __shared__ float r0[512], r1[512];
        float m0 = 0.f, m1 = 0.f;
        for (int i = t; i < nw; i += 512) {
            float2 v = partial[i];
            m0 += v.x; m1 += v.y;
        }
        r0[t] = m0; r1[t] = m1;
        __syncthreads();
        for (int o = 256; o > 0; o >>= 1) {
            if (t < o) { r0[t] += r0[t + o]; r1[t] += r1[t + o]; }
            __syncthreads();
        }
        if (t == 0) {
            float fm0 = r0[0] * einv, fm1 = r1[0] * einv;
            const float* We[3] = {We0, We1, We2};
            const float* ae[3] = {ae0, ae1, ae2};
            for (int l = 0; l < 3; ++l) {
                float c0 = 0.f, c1 = 0.f;
                for (int j = 0; j < 32; ++j) {
                    c0 += We[l][j] * ae[l][j];
                    c1 += We[l][32 + j] * ae[l][j];
                }
                consts[l * 2 + 0] = c0;
                consts[l * 2 + 1] = c1;
                consts[6 + l] = fm0 * c0 + fm1 * c1;
            }
        }
        return;
    }
    __shared__ int nh[256], ns[256];
    __shared__ uint2 rs[CAP];
    int s0 = bucket_base[k], s1 = bucket_base[k + 1];
    int cnt = s1 - s0;
    uint2 lv[12];
    if (t < 256) nh[t] = 0;
    __syncthreads();
#pragma unroll
    for (int u = 0; u < 12; ++u) {
        int i = s0 + u * 512 + t;
        if (i < s1) {
            uint2 v = st[i];
            lv[u] = v;
            atomicAdd(&nh[v.x & 255], 1);
        }
    }
    __syncthreads();
    if (t < 256) ns[t] = nh[t];
    __syncthreads();
    for (int o = 1; o < 256; o <<= 1) {
        int add = 0;
        if (t < 256 && t >= o) add = ns[t - o];
        __syncthreads();
        if (t < 256) ns[t] += add;
        __syncthreads();
    }
    int node0 = k << NBUCK_SHIFT;
    if (t < 256) {
        int startl = ns[t] - nh[t];
        if (node0 + t < n) rp[node0 + t] = s0 + startl;
        nh[t] = startl;
    }
    __syncthreads();
#pragma unroll
    for (int u = 0; u < 12; ++u) {
        int i = s0 + u * 512 + t;
        if (i < s1) {
            uint2 v = lv[u];
            int pos = atomicAdd(&nh[v.x & 255], 1);
            uint2 r = make_uint2(v.x >> NBUCK_SHIFT, v.y);  // flag lands at bit23
            if (pos < CAP) rs[pos] = r;
            else rec[s0 + pos] = r;      // overflow fallback (never in practice)
        }
    }
    __syncthreads();
    int m = cnt < CAP ? cnt : CAP;
    for (int i = t; i < m; i += 512)
        rec[s0 + i] = rs[i];
}

__device__ __forceinline__ float h2_get(const unsigned int* __restrict__ h2,
                                        int s, int word, bool hi) {
    unsigned int hw = h2[(size_t)s * 16 + word];
    __half2 hh = *reinterpret_cast<__half2*>(&hw);
    return hi ? __high2float(hh) : __low2float(hh);
}

// Fused edge-softmax + aggregation, 32-lane group per dst node (R8 body).
// rec.x: bit23 = self-loop flag (use consts[6+layer] logit), low bits = src.
// Epilogue: optional packed-half2 x store + per-node readout scalar (no atomics).
template <bool STORE_X>
__global__ void k_agg(const int* __restrict__ rp, const uint2* __restrict__ rec,
                      const float* __restrict__ asrc, const float* __restrict__ adst,
                      const float* __restrict__ consts, const unsigned int* __restrict__ h2,
                      const float* __restrict__ bb, unsigned int* __restrict__ xout,
                      const float* __restrict__ wl3, float* __restrict__ vout,
                      int n, int layer) {
    int node = blockIdx.x * 8 + (threadIdx.x >> 5);
    int j = threadIdx.x & 31;
    if (node >= n) return;
    float c0 = consts[layer * 2], c1 = consts[layer * 2 + 1];
    float loopc = consts[6 + layer];
    int r0 = rp[node], r1 = rp[node + 1];
    float adn = adst[node];
    int word = j >> 1;
    bool hi = (j & 1) != 0;
    float acc = 0.f, psum = 0.f;
    for (int c = r0; c < r1; c += 32) {
        int i = c + j;
        float pe = 0.f; int s = 0;
        if (i < r1) {
            unsigned long long rv = __builtin_nontemporal_load(
                reinterpret_cast<const unsigned long long*>(rec + i));
            unsigned int sx = (unsigned int)(rv & 0xffffffffull);
            s = (int)(sx & 0x7fffffu);
            unsigned int fv = (unsigned int)(rv >> 32);
            __half2 hh = *reinterpret_cast<__half2*>(&fv);
            float ae = (sx & SLF_BIT) ? loopc
                     : (__low2float(hh) * c0 + __high2float(hh) * c1);
            float lg = asrc[s] + adn + ae;
            lg = lg > 0.f ? lg : 0.2f * lg;
            pe = __expf(lg);
        }
        psum += pe;
        int cnt = min(32, r1 - c);
        int t = 0;
        for (; t + 8 <= cnt; t += 8) {
            int s0 = __shfl(s, t, 32),     s1 = __shfl(s, t + 1, 32);
            int s2 = __shfl(s, t + 2, 32), s3 = __shfl(s, t + 3, 32);
            int s4 = __shfl(s, t + 4, 32), s5 = __shfl(s, t + 5, 32);
            int s6 = __shfl(s, t + 6, 32), s7 = __shfl(s, t + 7, 32);
            float p0 = __shfl(pe, t, 32),     p1 = __shfl(pe, t + 1, 32);
            float p2 = __shfl(pe, t + 2, 32), p3 = __shfl(pe, t + 3, 32);
            float p4 = __shfl(pe, t + 4, 32), p5 = __shfl(pe, t + 5, 32);
            float p6 = __shfl(pe, t + 6, 32), p7 = __shfl(pe, t + 7, 32);
            float h0 = h2_get(h2, s0, word, hi);
            float h1 = h2_get(h2, s1, word, hi);
            float h2v = h2_get(h2, s2, word, hi);
            float h3 = h2_get(h2, s3, word, hi);
            float h4 = h2_get(h2, s4, word, hi);
            float h5 = h2_get(h2, s5, word, hi);
            float h6 = h2_get(h2, s6, word, hi);
            float h7 = h2_get(h2, s7, word, hi);
            acc += p0 * h0; acc += p1 * h1; acc += p2 * h2v; acc += p3 * h3;
            acc += p4 * h4; acc += p5 * h5; acc += p6 * h6; acc += p7 * h7;
        }
        for (; t + 4 <= cnt; t += 4) {
            int s0 = __shfl(s, t, 32),     s1 = __shfl(s, t + 1, 32);
            int s2 = __shfl(s, t + 2, 32), s3 = __shfl(s, t + 3, 32);
            float p0 = __shfl(pe, t, 32),     p1 = __shfl(pe, t + 1, 32);
            float p2 = __shfl(pe, t + 2, 32), p3 = __shfl(pe, t + 3, 32);
            float h0 = h2_get(h2, s0, word, hi);
            float h1 = h2_get(h2, s1, word, hi);
            float h2v = h2_get(h2, s2, word, hi);
            float h3 = h2_get(h2, s3, word, hi);
            acc += p0 * h0; acc += p1 * h1; acc += p2 * h2v; acc += p3 * h3;
        }
        for (; t < cnt; ++t) {
            int st2 = __shfl(s, t, 32);
            float pt = __shfl(pe, t, 32);
            acc += pt * h2_get(h2, st2, word, hi);
        }
    }
#pragma unroll
    for (int off = 16; off > 0; off >>= 1) psum += __shfl_xor(psum, off, 32);
    float res = acc / (psum + 1e-16f) + bb[j];
    if (STORE_X) {
        float resp = __shfl_down(res, 1, 32);
        if ((j & 1) == 0) {
            __half2 hh = __floats2half2_rn(res, resp);
            xout[(size_t)node * 16 + (j >> 1)] = *reinterpret_cast<unsigned int*>(&hh);
        }
    }
    float v = res * wl3[j];
#pragma unroll
    for (int off = 16; off > 0; off >>= 1) v += __shfl_xor(v, off, 32);
    if (j == 0) vout[node] = v;
}

// Readout: one block per graph, sums the three per-node scalars. 1.2MB total.
__global__ void k_dotv(const float* __restrict__ v0, const float* __restrict__ v1,
                       const float* __restrict__ v2, const int* __restrict__ bounds,
                       const float* __restrict__ bl3, float* __restrict__ out) {
    __shared__ float red[256];
    int g = blockIdx.x, t = threadIdx.x;
    int s0 = bounds[g], s1 = bounds[g + 1];
    float acc = 0.f;
    for (int i = s0 + t; i < s1; i += 256) acc += v0[i] + v1[i] + v2[i];
    red[t] = acc;
    __syncthreads();
    for (int o = 128; o > 0; o >>= 1) {
        if (t < o) red[t] += red[t + o];
        __syncthreads();
    }
    if (t == 0) {
        float c = (float)(s1 - s0);
        if (c < 1.f) c = 1.f;
        out[g] = red[0] / c + bl3[0];
    }
}

extern "C" void kernel_launch(void* const* d_in, const int* in_sizes, int n_in,
                              void* d_out, int out_size, void* d_ws, size_t ws_size,
                              hipStream_t stream) {
    (void)n_in; (void)out_size; (void)ws_size;
    const float* nf    = (const float*)d_in[0];
    const int*   ei    = (const int*)d_in[1];
    const float* ea    = (const float*)d_in[2];
    const int*   batch = (const int*)d_in[3];
    const float* W_ne  = (const float*)d_in[4];
    const float* b_ne  = (const float*)d_in[5];
    const float* W_ee  = (const float*)d_in[6];
    const float* b_ee  = (const float*)d_in[7];
    const float* W_l3  = (const float*)d_in[8];
    const float* b_l3  = (const float*)d_in[9];
    const float *Wl[3], *asl[3], *adl[3], *Wel[3], *ael[3], *bbl[3];
    for (int l = 0; l < 3; ++l) {
        Wl[l]  = (const float*)d_in[10 + 6 * l];
        asl[l] = (const float*)d_in[11 + 6 * l];
        adl[l] = (const float*)d_in[12 + 6 * l];
        Wel[l] = (const float*)d_in[13 + 6 * l];
        ael[l] = (const float*)d_in[14 + 6 * l];
        bbl[l] = (const float*)d_in[15 + 6 * l];
    }

    const int n  = in_sizes[3];        // 100000
    const int e  = in_sizes[2] / 3;    // 1600000
    const int ep = e + n;
    const int* ei0 = ei;
    const int* ei1 = ei + e;
    const int nbuck = (n + 255) >> NBUCK_SHIFT;   // 391

    char* w = (char*)d_ws;
    size_t off = 0;
    auto alloc = [&](size_t b) { size_t o = off; off = (off + b + 255) & ~(size_t)255; return o; };
    unsigned int* x1h     = (unsigned int*)(w + alloc((size_t)n * 16 * 4));
    unsigned int* x2h     = (unsigned int*)(w + alloc((size_t)n * 16 * 4));
    unsigned int* h2a     = (unsigned int*)(w + alloc((size_t)n * 16 * 4));
    unsigned int* h2b     = (unsigned int*)(w + alloc((size_t)n * 16 * 4));
    float*        asrcA   = (float*)(w + alloc((size_t)n * 4));
    float*        adstA   = (float*)(w + alloc((size_t)n * 4));
    float*        asrcB   = (float*)(w + alloc((size_t)n * 4));
    float*        adstB   = (float*)(w + alloc((size_t)n * 4));
    float*        v0      = (float*)(w + alloc((size_t)n * 4));
    float*        v1      = (float*)(w + alloc((size_t)n * 4));
    float*        v2      = (float*)(w + alloc((size_t)n * 4));
    uint2*        st      = (uint2*)(w + alloc((size_t)ep * 8));
    uint2*        rec     = (uint2*)(w + alloc((size_t)ep * 8));
    int*          rp      = (int*)(w + alloc((size_t)(n + 1) * 4));
    int*          bcnt    = (int*)(w + alloc(NBUCK_MAX * 4));
    int*          bbase   = (int*)(w + alloc((NBUCK_MAX + 1) * 4));
    int*          bcur    = (int*)(w + alloc(NBUCK_MAX * 4));
    float2*       partial = (float2*)(w + alloc((size_t)8192 * 8));
    float*        consts  = (float*)(w + alloc(256));
    int*          bounds  = (int*)(w + alloc(129 * 4));
    float*        wfbuf   = (float*)(w + alloc(320 * 4));

    hipMemsetAsync(bcnt, 0, NBUCK_MAX * 4, stream);

    int nbH = (ep + 4095) / 4096;        // 416
    int nw  = nbH * 4;                   // colsum partial slots (from binB)
    int nbN = (n + 7) / 8;               // 12500

    k_pre<<<nbH + 1, 256, 0, stream>>>(ei1, bcnt, batch, bounds,
                                       W_ne, b_ne, Wl[0], wfbuf, n, e, ep, nbH);
    k_hproj0<<<nbN, 256, 0, stream>>>(nf, wfbuf, asl[0], adl[0],
                                      h2a, asrcA, adstA, n);
    k_scan<<<1, 512, 0, stream>>>(bcnt, bbase, bcur, nbuck, ep, rp, n);
    k_binB<<<nbH, 256, 0, stream>>>(ei0, ei1, ea, W_ee, b_ee, bcur, st,
                                    partial, e, ep);
    k_binC<<<nbuck + 1, 512, 0, stream>>>(st, bbase, rp, rec, n, nbuck,
                                          Wel[0], ael[0], Wel[1], ael[1],
                                          Wel[2], ael[2], partial, nw,
                                          1.0f / (float)e, consts);

    // layer 0: h2a/A -> x1h, v0
    k_agg<true><<<nbN, 256, 0, stream>>>(rp, rec, asrcA, adstA, consts, h2a,
                                         bbl[0], x1h, W_l3 + 0, v0, n, 0);
    k_hproj<<<nbN, 256, 0, stream>>>(x1h, Wl[1], asl[1], adl[1], h2b, asrcB, adstB, n);
    // layer 1: h2b/B -> x2h, v1
    k_agg<true><<<nbN, 256, 0, stream>>>(rp, rec, asrcB, adstB, consts, h2b,
                                         bbl[1], x2h, W_l3 + 32, v1, n, 1);
    k_hproj<<<nbN, 256, 0, stream>>>(x2h, Wl[2], asl[2], adl[2], h2a, asrcA, adstA, n);
    // layer 2: h2a/A -> v2 only
    k_agg<false><<<nbN, 256, 0, stream>>>(rp, rec, asrcA, adstA, consts, h2a,
                                          bbl[2], nullptr, W_l3 + 64, v2, n, 2);
    k_dotv<<<128, 256, 0, stream>>>(v0, v1, v2, bounds, b_l3, (float*)d_out);
}